// Round 16
// baseline (78.737 us; speedup 1.0000x reference)
//
#include <hip/hip_runtime.h>

typedef _Float16 h2 __attribute__((ext_vector_type(2)));
typedef _Float16 h8 __attribute__((ext_vector_type(8)));
typedef float f4 __attribute__((ext_vector_type(4)));
typedef unsigned int uint32;

#define NVAL 20
#define CDIM 64
#define HW   65536
#define NPIX (4*HW)

#define BLK 256                   // 4 waves; each wave owns 64 consecutive pixels

// ---- packed f16 tables in ws (bytes) ----
#define KN_OFF      0
#define KN_KSTRIDE  2560          // per class: 20 j-rows x 128 B (c-contig, normalized)
#define VAL_OFF     (20*KN_KSTRIDE)      // 51200
#define VAL_KSTRIDE 4096          // per class: 64 c-rows x 64 B (32 j-slots)
#define VAL_CSTRIDE 64

#define ROW_STRIDE 144            // 64 f16 (128 B) + 16 pad; 16B-aligned rows

static __device__ __forceinline__ h2 bch2(uint32 u) { return __builtin_bit_cast(h2, u); }
static __device__ __forceinline__ uint32 bcu(h2 v) { return __builtin_bit_cast(uint32, v); }
static __device__ __forceinline__ h8 bch8(uint4 u) { return __builtin_bit_cast(h8, u); }
static __device__ __forceinline__ h2 pkrtz(float a, float b) {
    return __builtin_bit_cast(h2, __builtin_amdgcn_cvt_pkrtz(a, b));
}
static __device__ __forceinline__ uint4 sel4(bool p, uint4 v) {
    uint4 r;
    r.x = p ? v.x : 0u; r.y = p ? v.y : 0u;
    r.z = p ? v.z : 0u; r.w = p ? v.w : 0u;
    return r;
}
static __device__ __forceinline__ void wavefence() {
    asm volatile("s_waitcnt lgkmcnt(0)" ::: "memory");
    __builtin_amdgcn_wave_barrier();
}

// ---------------------------------------------------------------------------
// Prep: build packed f16 tables in ws (unchanged, verified since round 5).
// ---------------------------------------------------------------------------
__global__ void prep_kernel(const float* __restrict__ key,
                            const float* __restrict__ val,
                            unsigned char* __restrict__ ws) {
    int i = blockIdx.x * 256 + threadIdx.x;
    if (i < 20*CDIM) {
        int k = i >> 6, c = i & 63;
        const float* vb = val + k*NVAL*CDIM + c;     // val[k][j][c]
        float v[NVAL];
        float s = 0.f;
        #pragma unroll
        for (int j = 0; j < NVAL; j++) { v[j] = vb[j*CDIM]; s += v[j]; }
        float t = 0.f;
        for (int kk = 0; kk < 20; kk++) {
            const float* vb2 = val + kk*NVAL*CDIM + c;
            #pragma unroll
            for (int j = 0; j < NVAL; j++) t += vb2[j*CDIM];
        }
        float rest = (t - s) * (1.0f/NVAL);
        uint32* row = (uint32*)(ws + VAL_OFF + (size_t)k*VAL_KSTRIDE + c*VAL_CSTRIDE);
        #pragma unroll
        for (int jp = 0; jp < 10; jp++) row[jp] = bcu(pkrtz(v[2*jp], v[2*jp+1]));
        row[10] = bcu(pkrtz(rest, 0.f));
        #pragma unroll
        for (int jp = 11; jp < 16; jp++) row[jp] = 0u;
    } else if (i < 20*CDIM + 20*NVAL) {
        int idx = i - 20*CDIM;
        int k = idx / NVAL, j = idx % NVAL;
        const float* kb = key + k*CDIM*NVAL + j;     // key[k][c][j]
        float x[CDIM];
        float ssq = 0.f;
        #pragma unroll
        for (int c = 0; c < CDIM; c++) { x[c] = kb[c*NVAL]; ssq = fmaf(x[c], x[c], ssq); }
        float inv = 1.0f / fmaxf(sqrtf(ssq), 1e-12f);
        uint32* row = (uint32*)(ws + KN_OFF + (size_t)k*KN_KSTRIDE + j*128);
        #pragma unroll
        for (int cp = 0; cp < 32; cp++) row[cp] = bcu(pkrtz(x[2*cp]*inv, x[2*cp+1]*inv));
    }
}

// ---------------------------------------------------------------------------
// Main: 1024 blocks x 256 threads (4 blocks/CU, 16 waves/CU). NO SORT.
// Each wave independently handles 64 consecutive pixels:
//   stage (planar, pre-normalized f16 rows in own LDS slice) ->
//   k-sweep QK^T with class-masked B accumulation (only matching pixels'
//   columns contribute) -> softmax -> W via own rows -> k-sweep PV with
//   masked W -> O rows -> planar store.
// Zero block barriers / atomics / flags; 3 intra-wave lgkmcnt fences only.
// ---------------------------------------------------------------------------
__global__ __launch_bounds__(BLK, 4) void main_kernel(
        const float* __restrict__ content, const int* __restrict__ seg,
        const unsigned char* __restrict__ tabs, float* __restrict__ out) {
    __shared__ unsigned char lds[BLK * ROW_STRIDE];

    const int tid  = threadIdx.x;
    const int wave = tid >> 6, lane = tid & 63;
    const int g = lane >> 4, r16 = lane & 15;
    const int bid = (int)((blockIdx.x & 7) * 128 + (blockIdx.x >> 3));  // XCD swizzle
    const int gp0 = bid * BLK;
    const int b   = gp0 >> 16;
    const int pix = (gp0 & (HW - 1)) + tid;       // pixel offset within image
    const float* cptr = content + (size_t)b * CDIM * HW + pix;

    // ---- stage own pixel: batched planar loads, normalize in reg, own row ----
    {
        float xa[32], xc[32];
        #pragma unroll
        for (int j = 0; j < 32; j++) xa[j] = cptr[(size_t)j * HW];
        #pragma unroll
        for (int j = 0; j < 32; j++) xc[j] = cptr[(size_t)(32 + j) * HW];
        float ssq = 0.f;
        #pragma unroll
        for (int j = 0; j < 32; j++) ssq = fmaf(xa[j], xa[j], ssq);
        #pragma unroll
        for (int j = 0; j < 32; j++) ssq = fmaf(xc[j], xc[j], ssq);
        const float inv = 1.0f / fmaxf(sqrtf(ssq), 1e-12f);
        uint4* myrow = (uint4*)(lds + tid * ROW_STRIDE);
        #pragma unroll
        for (int q = 0; q < 4; q++) {
            uint4 o;
            o.x = bcu(pkrtz(xa[8*q+0]*inv, xa[8*q+1]*inv));
            o.y = bcu(pkrtz(xa[8*q+2]*inv, xa[8*q+3]*inv));
            o.z = bcu(pkrtz(xa[8*q+4]*inv, xa[8*q+5]*inv));
            o.w = bcu(pkrtz(xa[8*q+6]*inv, xa[8*q+7]*inv));
            myrow[q] = o;
        }
        #pragma unroll
        for (int q = 0; q < 4; q++) {
            uint4 o;
            o.x = bcu(pkrtz(xc[8*q+0]*inv, xc[8*q+1]*inv));
            o.y = bcu(pkrtz(xc[8*q+2]*inv, xc[8*q+3]*inv));
            o.z = bcu(pkrtz(xc[8*q+4]*inv, xc[8*q+5]*inv));
            o.w = bcu(pkrtz(xc[8*q+6]*inv, xc[8*q+7]*inv));
            myrow[q + 4] = o;
        }
    }
    const int mycls = seg[gp0 + tid] + 1;         // 1..19

    wavefence();                                  // own wave's rows visible

    int clsv[4];
    int rowb[4];
    #pragma unroll
    for (int n = 0; n < 4; n++) {
        clsv[n] = __shfl(mycls, n*16 + r16, 64);
        rowb[n] = (wave*64 + n*16 + r16) * ROW_STRIDE;
    }

    // B fragments of X (per subtile n)
    uint4 b_sc[4][2];
    #pragma unroll
    for (int n = 0; n < 4; n++)
        #pragma unroll
        for (int ks = 0; ks < 2; ks++)
            b_sc[n][ks] = *(const uint4*)(lds + rowb[n] + ks*64 + g*16);

    // ---- QK^T k-sweep with masked-B accumulation ----
    f4 sacc[2][4];
    #pragma unroll
    for (int m = 0; m < 2; m++)
        #pragma unroll
        for (int n = 0; n < 4; n++) sacc[m][n] = (f4){0.f,0.f,0.f,0.f};

    #pragma unroll 1
    for (int k = 1; k < 20; ++k) {
        bool an[4];
        #pragma unroll
        for (int n = 0; n < 4; n++) an[n] = __any(clsv[n] == k);
        if (!(an[0] | an[1] | an[2] | an[3])) continue;
        const unsigned char* knc = tabs + KN_OFF + (size_t)k * KN_KSTRIDE;
        uint4 ak[2][2];
        #pragma unroll
        for (int m = 0; m < 2; m++)
            #pragma unroll
            for (int ks = 0; ks < 2; ks++)
                ak[m][ks] = *(const uint4*)(knc + (m*16 + r16)*128 + ks*64 + g*16);
        #pragma unroll
        for (int n = 0; n < 4; n++) {
            if (!an[n]) continue;
            const bool p = (clsv[n] == k);
            uint4 mb0 = sel4(p, b_sc[n][0]);
            uint4 mb1 = sel4(p, b_sc[n][1]);
            sacc[0][n] = __builtin_amdgcn_mfma_f32_16x16x32_f16(bch8(ak[0][0]), bch8(mb0), sacc[0][n], 0, 0, 0);
            sacc[0][n] = __builtin_amdgcn_mfma_f32_16x16x32_f16(bch8(ak[0][1]), bch8(mb1), sacc[0][n], 0, 0, 0);
            sacc[1][n] = __builtin_amdgcn_mfma_f32_16x16x32_f16(bch8(ak[1][0]), bch8(mb0), sacc[1][n], 0, 0, 0);
            sacc[1][n] = __builtin_amdgcn_mfma_f32_16x16x32_f16(bch8(ak[1][1]), bch8(mb1), sacc[1][n], 0, 0, 0);
        }
    }

    // ---- softmax (rows pre-normalized: arg is raw score) ----
    uint2 w0[4], w1[4];
    #pragma unroll
    for (int n = 0; n < 4; n++) {
        float e0[4], e1[4];
        #pragma unroll
        for (int r = 0; r < 4; r++) e0[r] = __expf(sacc[0][n][r]);
        const float arg1 = (g == 0) ? 1.0f : 0.0f;     // j>=20 masked
        #pragma unroll
        for (int r = 0; r < 4; r++) e1[r] = __expf(sacc[1][n][r] * arg1);
        float sum = e0[0]+e0[1]+e0[2]+e0[3];
        sum += (g == 0) ? (e1[0]+e1[1]+e1[2]+e1[3]) : 0.0f;
        sum += __shfl_xor(sum, 16, 64);
        sum += __shfl_xor(sum, 32, 64);
        const float wsc = 1.0f / sum;
        w0[n].x = bcu(pkrtz(e0[0]*wsc, e0[1]*wsc));
        w0[n].y = bcu(pkrtz(e0[2]*wsc, e0[3]*wsc));
        uint2 t1;
        if (g == 0)      { t1.x = bcu(pkrtz(e1[0]*wsc, e1[1]*wsc));
                           t1.y = bcu(pkrtz(e1[2]*wsc, e1[3]*wsc)); }
        else if (g == 1) { t1.x = 0x00003C00u; t1.y = 0u; }  // j20=1.0 (rest)
        else             { t1.x = 0u; t1.y = 0u; }
        w1[n] = t1;
    }
    // write W over pixel rows (X is dead): j-contiguous 32 f16 at offset 0
    #pragma unroll
    for (int n = 0; n < 4; n++) {
        *(uint2*)(lds + rowb[n] + g*8)      = w0[n];
        *(uint2*)(lds + rowb[n] + 32 + g*8) = w1[n];
    }

    wavefence();                                  // W rows visible

    uint4 b_pv[4];
    #pragma unroll
    for (int n = 0; n < 4; n++)
        b_pv[n] = *(const uint4*)(lds + rowb[n] + g*16);

    // ---- PV k-sweep with masked-W accumulation ----
    f4 o[4][4];
    #pragma unroll
    for (int m = 0; m < 4; m++)
        #pragma unroll
        for (int n = 0; n < 4; n++) o[m][n] = (f4){0.f,0.f,0.f,0.f};

    #pragma unroll 1
    for (int k = 1; k < 20; ++k) {
        bool an[4];
        #pragma unroll
        for (int n = 0; n < 4; n++) an[n] = __any(clsv[n] == k);
        if (!(an[0] | an[1] | an[2] | an[3])) continue;
        const unsigned char* vc = tabs + VAL_OFF + (size_t)k * VAL_KSTRIDE;
        uint4 av[4];
        #pragma unroll
        for (int m = 0; m < 4; m++)
            av[m] = *(const uint4*)(vc + (m*16 + r16)*VAL_CSTRIDE + g*16);
        #pragma unroll
        for (int n = 0; n < 4; n++) {
            if (!an[n]) continue;
            const bool p = (clsv[n] == k);
            uint4 mbv = sel4(p, b_pv[n]);
            #pragma unroll
            for (int m = 0; m < 4; m++)
                o[m][n] = __builtin_amdgcn_mfma_f32_16x16x32_f16(bch8(av[m]), bch8(mbv), o[m][n], 0, 0, 0);
        }
    }

    // ---- O back to rows (f16), then planar coalesced store ----
    #pragma unroll
    for (int m = 0; m < 4; m++)
        #pragma unroll
        for (int n = 0; n < 4; n++) {
            uint2 ov;
            ov.x = bcu(pkrtz(o[m][n][0], o[m][n][1]));
            ov.y = bcu(pkrtz(o[m][n][2], o[m][n][3]));
            *(uint2*)(lds + rowb[n] + m*32 + g*8) = ov;   // c = m*16+g*4..+3
        }

    wavefence();                                  // O rows visible

    {
        const uint4* r4 = (const uint4*)(lds + tid * ROW_STRIDE);
        float* op = out + (size_t)b * CDIM * HW + pix;
        #pragma unroll
        for (int q = 0; q < 8; q++) {
            uint4 v = r4[q];
            h2 x = bch2(v.x), y = bch2(v.y), z = bch2(v.z), w = bch2(v.w);
            op[(size_t)(8*q+0) * HW] = (float)x[0];
            op[(size_t)(8*q+1) * HW] = (float)x[1];
            op[(size_t)(8*q+2) * HW] = (float)y[0];
            op[(size_t)(8*q+3) * HW] = (float)y[1];
            op[(size_t)(8*q+4) * HW] = (float)z[0];
            op[(size_t)(8*q+5) * HW] = (float)z[1];
            op[(size_t)(8*q+6) * HW] = (float)w[0];
            op[(size_t)(8*q+7) * HW] = (float)w[1];
        }
    }
}

extern "C" void kernel_launch(void* const* d_in, const int* in_sizes, int n_in,
                              void* d_out, int out_size, void* d_ws, size_t ws_size,
                              hipStream_t stream) {
    const float* content = (const float*)d_in[0];
    const int*   seg     = (const int*)d_in[1];
    const float* key     = (const float*)d_in[2];
    const float* val     = (const float*)d_in[3];
    float* out = (float*)d_out;
    unsigned char* ws = (unsigned char*)d_ws;

    prep_kernel<<<7, 256, 0, stream>>>(key, val, ws);
    main_kernel<<<NPIX/BLK, BLK, 0, stream>>>(content, seg, ws, out);
}

// Round 17
// 40.381 us; speedup vs baseline: 1.9498x; 1.9498x over previous
//
#include <hip/hip_runtime.h>

typedef _Float16 h2 __attribute__((ext_vector_type(2)));
typedef _Float16 h8 __attribute__((ext_vector_type(8)));
typedef float f4 __attribute__((ext_vector_type(4)));
typedef unsigned int uint32;

#define NVAL 20
#define CDIM 64
#define HW   65536
#define NPIX (4*HW)

#define BLK   1024
#define HALF  512
#define NW_G  8                   // waves per group
#define MAXT_H 28                 // tiles per 512-px half: sum ceil(n_k/64) <= 27
#define MSLOT_H (MAXT_H*64)       // 1792

// ---- packed f16 tables in ws (bytes) ----
#define KN_OFF      0
#define KN_KSTRIDE  2560          // per class: 20 j-rows x 128 B (c-contig, normalized)
#define VAL_OFF     (20*KN_KSTRIDE)      // 51200
#define VAL_KSTRIDE 4096          // per class: 64 c-rows x 64 B (32 j-slots)
#define VAL_CSTRIDE 64

// ---- LDS layout (bytes) ----
#define ROW_STRIDE 144            // 64 f16 (128 B) + 16 pad
#define ROWS_BYTES (BLK*ROW_STRIDE)          // 147456
#define INV_OFF   ROWS_BYTES                 // 1024 f32 -> 151552
#define PERM_OFF  (INV_OFF + BLK*4)          // 2*1792 u16 -> 158720
#define TCLS_OFF  (PERM_OFF + 2*MSLOT_H*2)   // 2*28 int -> 158944
#define FLAG_OFF  (TCLS_OFF + 2*MAXT_H*4)    // 2*28 int -> 159168
#define CNT_OFF   (FLAG_OFF + 2*MAXT_H*4)    // 2*24 int -> 159360
#define CTR_OFF   (CNT_OFF + 2*24*4)         // 4 int
#define LDS_TOTAL (CTR_OFF + 16)             // 159376 B <= 163840 OK

static __device__ __forceinline__ h2 bch2(uint32 u) { return __builtin_bit_cast(h2, u); }
static __device__ __forceinline__ uint32 bcu(h2 v) { return __builtin_bit_cast(uint32, v); }
static __device__ __forceinline__ h8 bch8(uint4 u) { return __builtin_bit_cast(h8, u); }
static __device__ __forceinline__ h2 pkrtz(float a, float b) {
    return __builtin_bit_cast(h2, __builtin_amdgcn_cvt_pkrtz(a, b));
}

// ---------------------------------------------------------------------------
// Prep: build packed f16 tables in ws (unchanged, verified since round 5).
// ---------------------------------------------------------------------------
__global__ void prep_kernel(const float* __restrict__ key,
                            const float* __restrict__ val,
                            unsigned char* __restrict__ ws) {
    int i = blockIdx.x * 256 + threadIdx.x;
    if (i < 20*CDIM) {
        int k = i >> 6, c = i & 63;
        const float* vb = val + k*NVAL*CDIM + c;     // val[k][j][c]
        float v[NVAL];
        float s = 0.f;
        #pragma unroll
        for (int j = 0; j < NVAL; j++) { v[j] = vb[j*CDIM]; s += v[j]; }
        float t = 0.f;
        for (int kk = 0; kk < 20; kk++) {
            const float* vb2 = val + kk*NVAL*CDIM + c;
            #pragma unroll
            for (int j = 0; j < NVAL; j++) t += vb2[j*CDIM];
        }
        float rest = (t - s) * (1.0f/NVAL);
        uint32* row = (uint32*)(ws + VAL_OFF + (size_t)k*VAL_KSTRIDE + c*VAL_CSTRIDE);
        #pragma unroll
        for (int jp = 0; jp < 10; jp++) row[jp] = bcu(pkrtz(v[2*jp], v[2*jp+1]));
        row[10] = bcu(pkrtz(rest, 0.f));
        #pragma unroll
        for (int jp = 11; jp < 16; jp++) row[jp] = 0u;
    } else if (i < 20*CDIM + 20*NVAL) {
        int idx = i - 20*CDIM;
        int k = idx / NVAL, j = idx % NVAL;
        const float* kb = key + k*CDIM*NVAL + j;     // key[k][c][j]
        float x[CDIM];
        float ssq = 0.f;
        #pragma unroll
        for (int c = 0; c < CDIM; c++) { x[c] = kb[c*NVAL]; ssq = fmaf(x[c], x[c], ssq); }
        float inv = 1.0f / fmaxf(sqrtf(ssq), 1e-12f);
        uint32* row = (uint32*)(ws + KN_OFF + (size_t)k*KN_KSTRIDE + j*128);
        #pragma unroll
        for (int cp = 0; cp < 32; cp++) row[cp] = bcu(pkrtz(x[2*cp]*inv, x[2*cp+1]*inv));
    }
}

// every thread redundantly scans the 20 counters: {my_base_slot, n_tiles}
static __device__ __forceinline__ int2 scan20(const int* cnt, int cls) {
    int acc = 0, mb = 0;
    #pragma unroll
    for (int k = 1; k <= 20; k++) {
        if (k == cls) mb = acc;
        acc += (cnt[k] + 63) & ~63;
    }
    return make_int2(mb, acc >> 6);
}

static __device__ __forceinline__ void gsync(int* ctr, int lane) {
    __threadfence_block();
    if (lane == 0)
        __hip_atomic_fetch_add(ctr, 1, __ATOMIC_ACQ_REL, __HIP_MEMORY_SCOPE_WORKGROUP);
    while (__hip_atomic_load(ctr, __ATOMIC_ACQUIRE, __HIP_MEMORY_SCOPE_WORKGROUP) < NW_G)
        __builtin_amdgcn_s_sleep(1);
}
static __device__ __forceinline__ void gwait(int* ctr) {
    while (__hip_atomic_load(ctr, __ATOMIC_ACQUIRE, __HIP_MEMORY_SCOPE_WORKGROUP) < NW_G)
        __builtin_amdgcn_s_sleep(1);
}

// ---------------------------------------------------------------------------
// Main: 256 blocks x 1024 threads (1 block/CU). Split-phase wave pipeline:
// waves 0-7 own pixels [0,512) ("A"), waves 8-15 own [512,1024) ("B"); each
// half has its own sort/flags/counters. B's start is skewed until A finishes
// staging, so B.stage overlaps A.middle and A.store overlaps B.middle.
// Group sync = LDS atomic counters + acquire spins (no block barriers after
// entry). Stage/middle/store are round-15-verbatim, parametrized per half.
// ---------------------------------------------------------------------------
__global__ __launch_bounds__(BLK) void main_kernel(
        const float* __restrict__ content, const int* __restrict__ seg,
        const unsigned char* __restrict__ tabs, float* __restrict__ out) {
    extern __shared__ unsigned char lds[];
    float* invA = (float*)(lds + INV_OFF);
    unsigned short* perm = (unsigned short*)(lds + PERM_OFF);
    int* tclsA  = (int*)(lds + TCLS_OFF);
    int* flagsA = (int*)(lds + FLAG_OFF);
    int* cntA   = (int*)(lds + CNT_OFF);
    int* ctr    = (int*)(lds + CTR_OFF);

    const int tid  = threadIdx.x;
    const int h    = tid >> 9;                    // 0 = group A, 1 = group B
    const int wave = tid >> 6, lane = tid & 63;
    const int gw   = wave & 7;                    // wave index within group
    const int g = lane >> 4, r16 = lane & 15;
    const int bid  = (int)((blockIdx.x & 7) * 32 + (blockIdx.x >> 3));  // XCD swizzle
    const int gp0  = bid * BLK;
    const int b    = gp0 >> 16;
    const int pim0 = gp0 & (HW - 1);
    float* obase = out + (size_t)b * CDIM * HW + pim0;

    unsigned short* permh = perm + h * MSLOT_H;
    int* tclsh  = tclsA  + h * MAXT_H;
    int* flagsh = flagsA + h * MAXT_H;
    int* cnth   = cntA   + h * 24;

    if (tid < 48) cntA[tid] = 0;
    if (tid < 2*MAXT_H) flagsA[tid] = 0;
    if (tid < 4) ctr[tid] = 0;
    for (int i = tid; i < 2*MSLOT_H; i += BLK) perm[i] = 0xFFFFu;
    __syncthreads();                              // only block-wide barrier

    if (h == 1) gwait(&ctr[0]);                   // skew: B waits for A.stage

    const int cls = seg[gp0 + tid] + 1;           // 1..19
    const int myrank = atomicAdd(&cnth[cls], 1);

    // stage own pixel -> own LDS row (f16 pairs, unnormalized) + inv (r15)
    {
        const float* cptr = content + (size_t)b * CDIM * HW + pim0 + tid;
        uint2* myrow = (uint2*)(lds + tid * ROW_STRIDE);
        float ssq = 0.f;
        #pragma unroll
        for (int hh = 0; hh < 2; hh++) {
            float xb[32];
            #pragma unroll
            for (int j = 0; j < 32; j++) xb[j] = cptr[(size_t)(hh*32 + j) * HW];
            #pragma unroll
            for (int j = 0; j < 32; j++) ssq = fmaf(xb[j], xb[j], ssq);
            #pragma unroll
            for (int q = 0; q < 8; q++) {
                uint2 o;
                o.x = bcu(pkrtz(xb[4*q+0], xb[4*q+1]));
                o.y = bcu(pkrtz(xb[4*q+2], xb[4*q+3]));
                myrow[hh*8 + q] = o;
            }
        }
        invA[tid] = 1.0f / fmaxf(sqrtf(ssq), 1e-12f);
    }
    gsync(&ctr[h], lane);                         // group stage+hist complete

    const int2 s = scan20(cnth, cls);             // (base slot, n tiles) of half
    const int myslot = s.x + myrank;
    const int mytile = myslot >> 6;
    {
        permh[myslot] = (unsigned short)tid;      // global tid (row index)
        tclsh[mytile] = cls;
    }
    gsync(&ctr[2 + h], lane);                     // perm/tcls complete

    const int nt = s.y;

    for (int t = gw; t < nt; t += NW_G) {
        const int u = __builtin_amdgcn_readfirstlane(tclsh[t]);

        int rowb[4];
        float invn[4];
        bool mine[4];
        #pragma unroll
        for (int n = 0; n < 4; n++) {
            int v = permh[t*64 + n*16 + r16];
            mine[n] = (v != 0xFFFF);
            int l = mine[n] ? v : (h * HALF);
            rowb[n] = l * ROW_STRIDE;
            invn[n] = invA[l];
        }

        // ---- issue ALL table loads for this tile up front (named regs) ----
        const unsigned char* knc = tabs + KN_OFF + (size_t)u * KN_KSTRIDE;
        const unsigned char* vc  = tabs + VAL_OFF + (size_t)u * VAL_KSTRIDE;
        uint4 a_sc[2][2];
        #pragma unroll
        for (int m = 0; m < 2; m++)
            #pragma unroll
            for (int ks = 0; ks < 2; ks++)
                a_sc[m][ks] = *(const uint4*)(knc + (m*16 + r16)*128 + (ks*32 + g*8)*2);
        uint4 apv0 = *(const uint4*)(vc + (0*16 + r16)*VAL_CSTRIDE + g*16);
        uint4 apv1 = *(const uint4*)(vc + (1*16 + r16)*VAL_CSTRIDE + g*16);
        uint4 apv2 = *(const uint4*)(vc + (2*16 + r16)*VAL_CSTRIDE + g*16);
        uint4 apv3 = *(const uint4*)(vc + (3*16 + r16)*VAL_CSTRIDE + g*16);

        uint4 b_sc[4][2];
        #pragma unroll
        for (int n = 0; n < 4; n++)
            #pragma unroll
            for (int ks = 0; ks < 2; ks++)
                b_sc[n][ks] = *(const uint4*)(lds + rowb[n] + (ks*32 + g*8)*2);

        // ---- scores S^T[j][p] = sum_c Kn^T[j][c] * X^T[c][p] ----
        f4 sacc[2][4];
        #pragma unroll
        for (int m = 0; m < 2; m++)
            #pragma unroll
            for (int n = 0; n < 4; n++) sacc[m][n] = (f4){0.f,0.f,0.f,0.f};
        #pragma unroll
        for (int ks = 0; ks < 2; ks++)
            #pragma unroll
            for (int m = 0; m < 2; m++)
                #pragma unroll
                for (int n = 0; n < 4; n++)
                    sacc[m][n] = __builtin_amdgcn_mfma_f32_16x16x32_f16(
                        bch8(a_sc[m][ks]), bch8(b_sc[n][ks]), sacc[m][n], 0, 0, 0);

        // ---- softmax; lane holds j = m*16 + g*4 + r for pixel p = n*16+r16 ----
        uint2 w0[4], w1[4];
        #pragma unroll
        for (int n = 0; n < 4; n++) {
            float e0[4], e1[4];
            #pragma unroll
            for (int r = 0; r < 4; r++) e0[r] = __expf(sacc[0][n][r] * invn[n]);
            float arg1 = (g == 0) ? invn[n] : 0.0f;     // j>=20 masked
            #pragma unroll
            for (int r = 0; r < 4; r++) e1[r] = __expf(sacc[1][n][r] * arg1);
            float sum = e0[0]+e0[1]+e0[2]+e0[3];
            sum += (g == 0) ? (e1[0]+e1[1]+e1[2]+e1[3]) : 0.0f;
            sum += __shfl_xor(sum, 16, 64);
            sum += __shfl_xor(sum, 32, 64);
            float wsc = 1.0f / sum;
            w0[n].x = bcu(pkrtz(e0[0]*wsc, e0[1]*wsc));
            w0[n].y = bcu(pkrtz(e0[2]*wsc, e0[3]*wsc));
            uint2 t1;
            if (g == 0)      { t1.x = bcu(pkrtz(e1[0]*wsc, e1[1]*wsc));
                               t1.y = bcu(pkrtz(e1[2]*wsc, e1[3]*wsc)); }
            else if (g == 1) { t1.x = 0x00003C00u; t1.y = 0u; }  // j20=1.0 (rest)
            else             { t1.x = 0u; t1.y = 0u; }
            w1[n] = t1;
        }
        // write W over own row (X is dead): j-contiguous 32 f16 at offset 0
        #pragma unroll
        for (int n = 0; n < 4; n++) {
            if (mine[n]) {
                *(uint2*)(lds + rowb[n] + g*8)      = w0[n];
                *(uint2*)(lds + rowb[n] + 32 + g*8) = w1[n];
            }
        }

        // ---- PV O^T[c][p] = sum_j V^T[c][j] * W^T[j][p] (K=32) ----
        uint4 b_pv[4];
        #pragma unroll
        for (int n = 0; n < 4; n++)
            b_pv[n] = *(const uint4*)(lds + rowb[n] + g*16);
        #pragma unroll
        for (int m = 0; m < 4; m++) {
            uint4 a = (m == 0) ? apv0 : (m == 1) ? apv1 : (m == 2) ? apv2 : apv3;
            #pragma unroll
            for (int n = 0; n < 4; n++) {
                f4 o = (f4){0.f,0.f,0.f,0.f};
                o = __builtin_amdgcn_mfma_f32_16x16x32_f16(bch8(a), bch8(b_pv[n]), o, 0, 0, 0);
                uint2 ov; ov.x = bcu(pkrtz(o[0], o[1])); ov.y = bcu(pkrtz(o[2], o[3]));
                if (mine[n])
                    *(uint2*)(lds + rowb[n] + m*32 + g*8) = ov;  // c = m*16+g*4..+3
            }
        }

        // tile t complete: publish
        __threadfence_block();
        if (lane == 0)
            __hip_atomic_store(&flagsh[t], 1, __ATOMIC_RELEASE, __HIP_MEMORY_SCOPE_WORKGROUP);
    }

    // self-service store: wait only for MY tile, then store own row (coalesced)
    while (__hip_atomic_load(&flagsh[mytile], __ATOMIC_ACQUIRE,
                             __HIP_MEMORY_SCOPE_WORKGROUP) == 0) {
        __builtin_amdgcn_s_sleep(1);
    }
    {
        const uint4* r4 = (const uint4*)(lds + tid * ROW_STRIDE);
        float* op = obase + tid;
        #pragma unroll
        for (int q = 0; q < 8; q++) {
            uint4 v = r4[q];
            h2 x = bch2(v.x), y = bch2(v.y), z = bch2(v.z), w = bch2(v.w);
            op[(size_t)(8*q+0) * HW] = (float)x[0];
            op[(size_t)(8*q+1) * HW] = (float)x[1];
            op[(size_t)(8*q+2) * HW] = (float)y[0];
            op[(size_t)(8*q+3) * HW] = (float)y[1];
            op[(size_t)(8*q+4) * HW] = (float)z[0];
            op[(size_t)(8*q+5) * HW] = (float)z[1];
            op[(size_t)(8*q+6) * HW] = (float)w[0];
            op[(size_t)(8*q+7) * HW] = (float)w[1];
        }
    }
}

extern "C" void kernel_launch(void* const* d_in, const int* in_sizes, int n_in,
                              void* d_out, int out_size, void* d_ws, size_t ws_size,
                              hipStream_t stream) {
    const float* content = (const float*)d_in[0];
    const int*   seg     = (const int*)d_in[1];
    const float* key     = (const float*)d_in[2];
    const float* val     = (const float*)d_in[3];
    float* out = (float*)d_out;
    unsigned char* ws = (unsigned char*)d_ws;

    prep_kernel<<<7, 256, 0, stream>>>(key, val, ws);

    (void)hipFuncSetAttribute((const void*)main_kernel,
                              hipFuncAttributeMaxDynamicSharedMemorySize, LDS_TOTAL);
    main_kernel<<<NPIX/BLK, BLK, LDS_TOTAL, stream>>>(content, seg, ws, out);
}